// Round 10
// baseline (82.603 us; speedup 1.0000x reference)
//
#include <hip/hip_runtime.h>

#define N_NODES 10000
#define N_PAD   10048          // multiple of 64 for BM=64 tiles
#define N_EDGES 160000
#define DIM     512
#define KDIM    1024           // concatenated K = [h | neigh]
#define CAP     64             // per-node edge bucket capacity (max deg ~35)

#define BM 64
#define BN 128
#define BK 64
#define KITERS (KDIM / BK)     // 16

typedef __attribute__((ext_vector_type(8))) short bf16x8;
typedef __attribute__((ext_vector_type(4))) float f32x4;

static __device__ __forceinline__ ushort f2bf(float f) {
    union { float f; unsigned u; } x; x.f = f;
    unsigned u = x.u + 0x7fff + ((x.u >> 16) & 1);   // round-to-nearest-even
    return (ushort)(u >> 16);
}
static __device__ __forceinline__ float b2f(ushort u) {
    union { unsigned u; float f; } x; x.u = ((unsigned)u) << 16; return x.f;
}

// ---------------------------------------------------------------------------
// conv_w: Wc[c][k] = bf16([Wself | Wneigh]); also zeroes cnt (runs first).
// ---------------------------------------------------------------------------
__global__ __launch_bounds__(256) void conv_w(
    const float* __restrict__ Wself, const float* __restrict__ Wneigh,
    ushort* __restrict__ Wc, int* __restrict__ cnt)
{
    int idx = blockIdx.x * 256 + threadIdx.x;     // over 512*128 = 65536
    if (idx < N_NODES) cnt[idx] = 0;
    int c  = idx >> 7;
    int k8 = idx & 127;
    const float* src = (k8 < 64) ? (Wself + (size_t)c * DIM + k8 * 8)
                                 : (Wneigh + (size_t)c * DIM + (k8 - 64) * 8);
    float4 v0 = *(const float4*)src;
    float4 v1 = *(const float4*)(src + 4);
    ushort* dst = Wc + (size_t)c * KDIM + k8 * 8;
    ushort4 o0 = { f2bf(v0.x), f2bf(v0.y), f2bf(v0.z), f2bf(v0.w) };
    ushort4 o1 = { f2bf(v1.x), f2bf(v1.y), f2bf(v1.z), f2bf(v1.w) };
    *(ushort4*)dst = o0;
    *(ushort4*)(dst + 4) = o1;
}

// ---------------------------------------------------------------------------
// conv_x: left half of X = bf16(h); pad rows zeroed.  First N_EDGES threads
// also bucket the edges: p = atomicAdd(cnt[src]), col[src*CAP+p] = dst.
// ---------------------------------------------------------------------------
__global__ __launch_bounds__(256) void conv_x(
    const float* __restrict__ h, ushort* __restrict__ X,
    const int* __restrict__ eidx, int* __restrict__ cnt, int* __restrict__ col)
{
    int idx = blockIdx.x * 256 + threadIdx.x;
    if (idx < N_EDGES) {
        int s = eidx[idx];
        int d = eidx[N_EDGES + idx];
        int p = atomicAdd(&cnt[s], 1);
        if (p < CAP) col[(s << 6) + p] = d;
    }
    int n  = idx >> 7;
    int k8 = idx & 127;
    if (n >= N_PAD) return;
    ushort* dst = X + (size_t)n * KDIM + k8 * 8;
    if (n >= N_NODES) {                      // zero pad row (full 1024)
        ushort4 z = {0, 0, 0, 0};
        *(ushort4*)dst = z;
        *(ushort4*)(dst + 4) = z;
        return;
    }
    if (k8 >= 64) return;                    // right half written by gather
    const float* src = h + (size_t)n * DIM + k8 * 8;
    float4 v0 = *(const float4*)src;
    float4 v1 = *(const float4*)(src + 4);
    ushort4 o0 = { f2bf(v0.x), f2bf(v0.y), f2bf(v0.z), f2bf(v0.w) };
    ushort4 o1 = { f2bf(v1.x), f2bf(v1.y), f2bf(v1.z), f2bf(v1.w) };
    *(ushort4*)dst = o0;
    *(ushort4*)(dst + 4) = o1;
}

// ---------------------------------------------------------------------------
// Gather-aggregate: one wave per node; lane owns cols lane*8..+7 (16B).
// Bucketed edge list (<=CAP per node) broadcast via shfl; unroll x8 MLP.
// ---------------------------------------------------------------------------
__global__ __launch_bounds__(256) void gather_agg(
    const int* __restrict__ cnt, const int* __restrict__ col,
    ushort* __restrict__ X, float* __restrict__ deg)
{
    int gid  = blockIdx.x * 256 + threadIdx.x;
    int n    = gid >> 6;
    int lane = gid & 63;
    if (n >= N_NODES) return;
    int d  = cnt[n];
    int nk = d < CAP ? d : CAP;

    int myc = (lane < nk) ? col[(n << 6) + lane] : 0;

    float s0 = 0.f, s1 = 0.f, s2 = 0.f, s3 = 0.f;
    float s4 = 0.f, s5 = 0.f, s6 = 0.f, s7 = 0.f;
    int k = 0;
    for (; k + 8 <= nk; k += 8) {
        bf16x8 v[8];
#pragma unroll
        for (int u = 0; u < 8; ++u) {
            int dst = __shfl(myc, k + u);
            v[u] = *(const bf16x8*)(X + (size_t)dst * KDIM + lane * 8);
        }
#pragma unroll
        for (int u = 0; u < 8; ++u) {
            s0 += b2f((ushort)v[u][0]); s1 += b2f((ushort)v[u][1]);
            s2 += b2f((ushort)v[u][2]); s3 += b2f((ushort)v[u][3]);
            s4 += b2f((ushort)v[u][4]); s5 += b2f((ushort)v[u][5]);
            s6 += b2f((ushort)v[u][6]); s7 += b2f((ushort)v[u][7]);
        }
    }
    for (; k < nk; ++k) {
        int dst = __shfl(myc, k);
        bf16x8 v = *(const bf16x8*)(X + (size_t)dst * KDIM + lane * 8);
        s0 += b2f((ushort)v[0]); s1 += b2f((ushort)v[1]);
        s2 += b2f((ushort)v[2]); s3 += b2f((ushort)v[3]);
        s4 += b2f((ushort)v[4]); s5 += b2f((ushort)v[5]);
        s6 += b2f((ushort)v[6]); s7 += b2f((ushort)v[7]);
    }
    float inv = 1.0f / fmaxf((float)d, 1.0f);
    ushort* xr = X + (size_t)n * KDIM + DIM + lane * 8;
    ushort4 o0 = { f2bf(s0 * inv), f2bf(s1 * inv), f2bf(s2 * inv), f2bf(s3 * inv) };
    ushort4 o1 = { f2bf(s4 * inv), f2bf(s5 * inv), f2bf(s6 * inv), f2bf(s7 * inv) };
    *(ushort4*)xr       = o0;
    *(ushort4*)(xr + 4) = o1;
    if (lane == 0) deg[n] = (float)d;
}

// ---------------------------------------------------------------------------
// MFMA GEMM: 128 thr / 2 waves, tile 64x128, wave tile 64x64.
// Per wave-K-step: 8 ds_read_b128 vs 32 MFMA (0.25 reads/MFMA per inner) --
// LDS-pipe ~250 cyc vs MFMA ~258 cyc per block K-step: balanced (was 375:258).
// global_load_lds(16B) staging, XOR-swizzled source, dbuf, 1 barrier/K-step.
// Grid (col, row): col-blocks of a row-group dispatch-adjacent for L2 reuse.
// ---------------------------------------------------------------------------
#define MFMA(A, B, C) __builtin_amdgcn_mfma_f32_16x16x32_bf16(A, B, C, 0, 0, 0)

__global__ __launch_bounds__(128) void mfma_gemm(
    const ushort* __restrict__ X, const ushort* __restrict__ Wc,
    const float* __restrict__ deg,
    const float* __restrict__ bself, const float* __restrict__ bneigh,
    ushort* __restrict__ Y)
{
    __shared__ ushort As[2][BM * BK];    // 2 x  8 KB, linear (DMA dest)
    __shared__ ushort Bs[2][BN * BK];    // 2 x 16 KB
    __shared__ float  hb_s[BM];

    const int t    = threadIdx.x;        // 0..127
    const int lane = t & 63;
    const int wave = t >> 6;             // 0..1
    const int row0 = blockIdx.y * BM;
    const int col0 = blockIdx.x * BN;
    const int wc   = wave * 64;          // wave col offset
    const int fr   = lane & 15;
    const int fq   = lane >> 4;          // 0..3

    if (t < BM) {
        int n = row0 + t;
        hb_s[t] = (n < N_NODES && deg[n] > 0.0f) ? 1.0f : 0.0f;
    }

#define STAGE(BUF, IT)                                                         \
    {                                                                          \
        const int k0s = (IT) * BK;                                             \
        _Pragma("unroll")                                                      \
        for (int s = 0; s < 4; ++s) {                                          \
            int c = t + s * 128;                                               \
            int row = c >> 3;                                                  \
            int ks = k0s + (((c & 7) ^ (row & 7)) << 3);                       \
            __builtin_amdgcn_global_load_lds(                                  \
                (const __attribute__((address_space(1))) void*)                \
                    (X + (size_t)(row0 + row) * KDIM + ks),                    \
                (__attribute__((address_space(3))) void*)(&As[BUF][c * 8]),    \
                16, 0, 0);                                                     \
        }                                                                      \
        _Pragma("unroll")                                                      \
        for (int s = 0; s < 8; ++s) {                                          \
            int c = t + s * 128;                                               \
            int row = c >> 3;                                                  \
            int ks = k0s + (((c & 7) ^ (row & 7)) << 3);                       \
            __builtin_amdgcn_global_load_lds(                                  \
                (const __attribute__((address_space(1))) void*)                \
                    (Wc + (size_t)(col0 + row) * KDIM + ks),                   \
                (__attribute__((address_space(3))) void*)(&Bs[BUF][c * 8]),    \
                16, 0, 0);                                                     \
        }                                                                      \
    }

    f32x4 acc[4][4];
#pragma unroll
    for (int i = 0; i < 4; ++i)
#pragma unroll
        for (int j = 0; j < 4; ++j) acc[i][j] = (f32x4){0.f, 0.f, 0.f, 0.f};

    STAGE(0, 0);
    __syncthreads();                     // drains vmcnt(0) + barrier

    int buf = 0;
    for (int it = 0; it < KITERS; ++it) {
        if (it + 1 < KITERS) STAGE(buf ^ 1, it + 1);   // async, overlaps MFMAs

        const ushort* as = As[buf];
        const ushort* bs = Bs[buf];
#pragma unroll
        for (int inner = 0; inner < 2; ++inner) {
            const int sw = (((inner * 4 + fq) ^ (fr & 7)) << 3);  // swizzled k-off
            bf16x8 a[4], b[4];
#pragma unroll
            for (int i = 0; i < 4; ++i)
                a[i] = *(const bf16x8*)(as + (i * 16 + fr) * BK + sw);
#pragma unroll
            for (int j = 0; j < 4; ++j)
                b[j] = *(const bf16x8*)(bs + (wc + j * 16 + fr) * BK + sw);
#pragma unroll
            for (int i = 0; i < 4; ++i)
#pragma unroll
                for (int j = 0; j < 4; ++j)
                    acc[i][j] = MFMA(a[i], b[j], acc[i][j]);
        }
        __syncthreads();                 // next-tile DMA drained; reads done
        buf ^= 1;
    }

    // epilogue: Y = bf16( relu(acc + bself + (deg>0)*bneigh) )
#pragma unroll
    for (int i = 0; i < 4; ++i) {
#pragma unroll
        for (int r = 0; r < 4; ++r) {
            int lr = i * 16 + fq * 4 + r;
            int gr = row0 + lr;
            float hb = hb_s[lr];
            ushort* yrow = Y + (size_t)gr * DIM;
#pragma unroll
            for (int j = 0; j < 4; ++j) {
                int gc = col0 + wc + j * 16 + fr;
                float v = fmaxf(acc[i][j][r] + bself[gc] + hb * bneigh[gc], 0.f);
                yrow[gc] = f2bf(v);
            }
        }
    }
}

// ---------------------------------------------------------------------------
// LayerNorm: out = LN(h + Y), one 256-thread block per node row.
// ---------------------------------------------------------------------------
__global__ __launch_bounds__(256) void ln_kernel(
    const ushort* __restrict__ Y, const float* __restrict__ h,
    const float* __restrict__ g, const float* __restrict__ b,
    float* __restrict__ out)
{
    __shared__ float red[8];
    int n = blockIdx.x;
    int t = threadIdx.x;
    float2 hv = *(const float2*)(h + (size_t)n * DIM + t * 2);
    ushort2 yv = *(const ushort2*)(Y + (size_t)n * DIM + t * 2);
    float v0 = hv.x + b2f(yv.x);
    float v1 = hv.y + b2f(yv.y);
    float s  = v0 + v1;
    float sq = v0 * v0 + v1 * v1;
#pragma unroll
    for (int off = 32; off >= 1; off >>= 1) {
        s  += __shfl_xor(s, off);
        sq += __shfl_xor(sq, off);
    }
    int wave = t >> 6;
    if ((t & 63) == 0) { red[wave] = s; red[4 + wave] = sq; }
    __syncthreads();
    s  = red[0] + red[1] + red[2] + red[3];
    sq = red[4] + red[5] + red[6] + red[7];
    float mean = s * (1.0f / DIM);
    float var  = sq * (1.0f / DIM) - mean * mean;
    float rstd = rsqrtf(var + 1e-5f);
    float2 gv = *(const float2*)(g + t * 2);
    float2 bv = *(const float2*)(b + t * 2);
    float2 o;
    o.x = (v0 - mean) * rstd * gv.x + bv.x;
    o.y = (v1 - mean) * rstd * gv.y + bv.y;
    *(float2*)(out + (size_t)n * DIM + t * 2) = o;
}

// ---------------------------------------------------------------------------
extern "C" void kernel_launch(void* const* d_in, const int* in_sizes, int n_in,
                              void* d_out, int out_size, void* d_ws, size_t ws_size,
                              hipStream_t stream)
{
    const float* h      = (const float*)d_in[0];
    const int*   eidx   = (const int*)d_in[1];
    const float* Wself  = (const float*)d_in[2];
    const float* bself  = (const float*)d_in[3];
    const float* Wneigh = (const float*)d_in[4];
    const float* bneigh = (const float*)d_in[5];
    const float* gamma  = (const float*)d_in[6];
    const float* beta   = (const float*)d_in[7];
    float* out = (float*)d_out;

    // ws layout: X (20.6MB) | Wc (1MB) | Y (10.3MB) | deg | cnt | col
    ushort* X   = (ushort*)d_ws;                          // N_PAD*KDIM bf16
    ushort* Wc  = X + (size_t)N_PAD * KDIM;               // 512*KDIM bf16
    ushort* Y   = Wc + (size_t)DIM * KDIM;                // N_PAD*DIM bf16
    float* deg  = (float*)(Y + (size_t)N_PAD * DIM);      // N f32
    int* cnt    = (int*)(deg + N_NODES);                  // N int
    int* col    = cnt + N_NODES;                          // N*CAP int (2.56MB)

    conv_w<<<(DIM * 128) / 256, 256, 0, stream>>>(Wself, Wneigh, Wc, cnt);
    conv_x<<<(N_PAD * 128) / 256, 256, 0, stream>>>(h, X, eidx, cnt, col);
    gather_agg<<<(N_NODES * 64) / 256, 256, 0, stream>>>(cnt, col, X, deg);

    dim3 gg(DIM / BN, N_PAD / BM);    // (4, 157): col-blocks adjacent
    mfma_gemm<<<gg, 128, 0, stream>>>(X, Wc, deg, bself, bneigh, Y);

    ln_kernel<<<N_NODES, 256, 0, stream>>>(Y, h, gamma, beta, out);
}

// Round 11
// 77.326 us; speedup vs baseline: 1.0683x; 1.0683x over previous
//
#include <hip/hip_runtime.h>
#include <hip/hip_fp8.h>

#define N_NODES 10000
#define N_PAD   10048          // multiple of 64 for BM=64 tiles
#define N_EDGES 160000
#define DIM     512
#define KDIM    1024           // concatenated K = [h | neigh]
#define CAP     64             // per-node edge bucket capacity (max deg ~35)

#define BM 64
#define BN 128
#define BK 64
#define KITERS (KDIM / BK)     // 16

typedef __attribute__((ext_vector_type(8))) short bf16x8;
typedef __attribute__((ext_vector_type(4))) float f32x4;

static __device__ __forceinline__ ushort f2bf(float f) {
    union { float f; unsigned u; } x; x.f = f;
    unsigned u = x.u + 0x7fff + ((x.u >> 16) & 1);   // round-to-nearest-even
    return (ushort)(u >> 16);
}
static __device__ __forceinline__ float b2f(ushort u) {
    union { unsigned u; float f; } x; x.u = ((unsigned)u) << 16; return x.f;
}
static __device__ __forceinline__ unsigned char f2fp8(float f) {
    __hip_fp8_e4m3 q(f);
    return (unsigned char)q.__x;
}
static __device__ __forceinline__ float fp82f(unsigned b) {
    __hip_fp8_e4m3 q;
    q.__x = (__hip_fp8_storage_t)b;
    return (float)q;
}

// ---------------------------------------------------------------------------
// conv_w: Wc[c][k] = bf16([Wself | Wneigh]); also zeroes cnt (runs first).
// ---------------------------------------------------------------------------
__global__ __launch_bounds__(256) void conv_w(
    const float* __restrict__ Wself, const float* __restrict__ Wneigh,
    ushort* __restrict__ Wc, int* __restrict__ cnt)
{
    int idx = blockIdx.x * 256 + threadIdx.x;     // over 512*128 = 65536
    if (idx < N_NODES) cnt[idx] = 0;
    int c  = idx >> 7;
    int k8 = idx & 127;
    const float* src = (k8 < 64) ? (Wself + (size_t)c * DIM + k8 * 8)
                                 : (Wneigh + (size_t)c * DIM + (k8 - 64) * 8);
    float4 v0 = *(const float4*)src;
    float4 v1 = *(const float4*)(src + 4);
    ushort* dst = Wc + (size_t)c * KDIM + k8 * 8;
    ushort4 o0 = { f2bf(v0.x), f2bf(v0.y), f2bf(v0.z), f2bf(v0.w) };
    ushort4 o1 = { f2bf(v1.x), f2bf(v1.y), f2bf(v1.z), f2bf(v1.w) };
    *(ushort4*)dst = o0;
    *(ushort4*)(dst + 4) = o1;
}

// ---------------------------------------------------------------------------
// conv_x: left half of X = bf16(h) AND H8 = fp8(h); pad rows zeroed.
// First N_EDGES threads also bucket edges: col[src*CAP + p] = dst.
// ---------------------------------------------------------------------------
__global__ __launch_bounds__(256) void conv_x(
    const float* __restrict__ h, ushort* __restrict__ X,
    unsigned char* __restrict__ H8,
    const int* __restrict__ eidx, int* __restrict__ cnt, int* __restrict__ col)
{
    int idx = blockIdx.x * 256 + threadIdx.x;
    if (idx < N_EDGES) {
        int s = eidx[idx];
        int d = eidx[N_EDGES + idx];
        int p = atomicAdd(&cnt[s], 1);
        if (p < CAP) col[(s << 6) + p] = d;
    }
    int n  = idx >> 7;
    int k8 = idx & 127;
    if (n >= N_PAD) return;
    ushort* dst = X + (size_t)n * KDIM + k8 * 8;
    if (n >= N_NODES) {                      // zero pad row (full 1024)
        ushort4 z = {0, 0, 0, 0};
        *(ushort4*)dst = z;
        *(ushort4*)(dst + 4) = z;
        return;
    }
    if (k8 >= 64) return;                    // right half written by gather
    const float* src = h + (size_t)n * DIM + k8 * 8;
    float4 v0 = *(const float4*)src;
    float4 v1 = *(const float4*)(src + 4);
    ushort4 o0 = { f2bf(v0.x), f2bf(v0.y), f2bf(v0.z), f2bf(v0.w) };
    ushort4 o1 = { f2bf(v1.x), f2bf(v1.y), f2bf(v1.z), f2bf(v1.w) };
    *(ushort4*)dst = o0;
    *(ushort4*)(dst + 4) = o1;
    // fp8 copy for the gather (halves gather read traffic)
    uint2 p8;
    p8.x = (unsigned)f2fp8(v0.x) | ((unsigned)f2fp8(v0.y) << 8) |
           ((unsigned)f2fp8(v0.z) << 16) | ((unsigned)f2fp8(v0.w) << 24);
    p8.y = (unsigned)f2fp8(v1.x) | ((unsigned)f2fp8(v1.y) << 8) |
           ((unsigned)f2fp8(v1.z) << 16) | ((unsigned)f2fp8(v1.w) << 24);
    *(uint2*)(H8 + (size_t)n * DIM + k8 * 8) = p8;
}

// ---------------------------------------------------------------------------
// Gather-aggregate (fp8 source): one wave per node; lane owns cols
// lane*8..+7 (8 B/edge).  Bucketed edges broadcast via shfl; unroll x8.
// Sum in f32, mean written bf16 into X right half.
// ---------------------------------------------------------------------------
__global__ __launch_bounds__(256) void gather_agg(
    const int* __restrict__ cnt, const int* __restrict__ col,
    const unsigned char* __restrict__ H8,
    ushort* __restrict__ X, float* __restrict__ deg)
{
    int gid  = blockIdx.x * 256 + threadIdx.x;
    int n    = gid >> 6;
    int lane = gid & 63;
    if (n >= N_NODES) return;
    int d  = cnt[n];
    int nk = d < CAP ? d : CAP;

    int myc = (lane < nk) ? col[(n << 6) + lane] : 0;

    float s0 = 0.f, s1 = 0.f, s2 = 0.f, s3 = 0.f;
    float s4 = 0.f, s5 = 0.f, s6 = 0.f, s7 = 0.f;
    int k = 0;
    for (; k + 8 <= nk; k += 8) {
        uint2 v[8];
#pragma unroll
        for (int u = 0; u < 8; ++u) {
            int dst = __shfl(myc, k + u);
            v[u] = *(const uint2*)(H8 + (size_t)dst * DIM + lane * 8);
        }
#pragma unroll
        for (int u = 0; u < 8; ++u) {
            s0 += fp82f(v[u].x & 0xff);         s1 += fp82f((v[u].x >> 8) & 0xff);
            s2 += fp82f((v[u].x >> 16) & 0xff); s3 += fp82f(v[u].x >> 24);
            s4 += fp82f(v[u].y & 0xff);         s5 += fp82f((v[u].y >> 8) & 0xff);
            s6 += fp82f((v[u].y >> 16) & 0xff); s7 += fp82f(v[u].y >> 24);
        }
    }
    for (; k < nk; ++k) {
        int dst = __shfl(myc, k);
        uint2 v = *(const uint2*)(H8 + (size_t)dst * DIM + lane * 8);
        s0 += fp82f(v.x & 0xff);         s1 += fp82f((v.x >> 8) & 0xff);
        s2 += fp82f((v.x >> 16) & 0xff); s3 += fp82f(v.x >> 24);
        s4 += fp82f(v.y & 0xff);         s5 += fp82f((v.y >> 8) & 0xff);
        s6 += fp82f((v.y >> 16) & 0xff); s7 += fp82f(v.y >> 24);
    }
    float inv = 1.0f / fmaxf((float)d, 1.0f);
    ushort* xr = X + (size_t)n * KDIM + DIM + lane * 8;
    ushort4 o0 = { f2bf(s0 * inv), f2bf(s1 * inv), f2bf(s2 * inv), f2bf(s3 * inv) };
    ushort4 o1 = { f2bf(s4 * inv), f2bf(s5 * inv), f2bf(s6 * inv), f2bf(s7 * inv) };
    *(ushort4*)xr       = o0;
    *(ushort4*)(xr + 4) = o1;
    if (lane == 0) deg[n] = (float)d;
}

// ---------------------------------------------------------------------------
// MFMA GEMM (R9 config): 256 thr / 4 waves (2x2), tile 64x128, wave 32x64.
// global_load_lds(16B) staging, XOR-swizzled source, dbuf, 1 barrier/K-step.
// Grid (col, row): col-blocks of a row-group dispatch-adjacent for L2 reuse.
// ---------------------------------------------------------------------------
#define MFMA(A, B, C) __builtin_amdgcn_mfma_f32_16x16x32_bf16(A, B, C, 0, 0, 0)

__global__ __launch_bounds__(256) void mfma_gemm(
    const ushort* __restrict__ X, const ushort* __restrict__ Wc,
    const float* __restrict__ deg,
    const float* __restrict__ bself, const float* __restrict__ bneigh,
    ushort* __restrict__ Y)
{
    __shared__ ushort As[2][BM * BK];    // 2 x  8 KB, linear (DMA dest)
    __shared__ ushort Bs[2][BN * BK];    // 2 x 16 KB

    const int t    = threadIdx.x;
    const int lane = t & 63;
    const int wave = t >> 6;
    const int row0 = blockIdx.y * BM;
    const int col0 = blockIdx.x * BN;
    const int wr   = (wave >> 1) * 32;   // wave row offset in tile
    const int wc   = (wave & 1) * 64;    // wave col offset in tile
    const int fr   = lane & 15;
    const int fq   = lane >> 4;          // 0..3

#define STAGE(BUF, IT)                                                         \
    {                                                                          \
        const int k0s = (IT) * BK;                                             \
        _Pragma("unroll")                                                      \
        for (int s = 0; s < 2; ++s) {                                          \
            int c = t + s * 256;                                               \
            int row = c >> 3;                                                  \
            int ks = k0s + (((c & 7) ^ (row & 7)) << 3);                       \
            __builtin_amdgcn_global_load_lds(                                  \
                (const __attribute__((address_space(1))) void*)                \
                    (X + (size_t)(row0 + row) * KDIM + ks),                    \
                (__attribute__((address_space(3))) void*)(&As[BUF][c * 8]),    \
                16, 0, 0);                                                     \
        }                                                                      \
        _Pragma("unroll")                                                      \
        for (int s = 0; s < 4; ++s) {                                          \
            int c = t + s * 256;                                               \
            int row = c >> 3;                                                  \
            int ks = k0s + (((c & 7) ^ (row & 7)) << 3);                       \
            __builtin_amdgcn_global_load_lds(                                  \
                (const __attribute__((address_space(1))) void*)                \
                    (Wc + (size_t)(col0 + row) * KDIM + ks),                   \
                (__attribute__((address_space(3))) void*)(&Bs[BUF][c * 8]),    \
                16, 0, 0);                                                     \
        }                                                                      \
    }

    f32x4 acc[2][4];
#pragma unroll
    for (int i = 0; i < 2; ++i)
#pragma unroll
        for (int j = 0; j < 4; ++j) acc[i][j] = (f32x4){0.f, 0.f, 0.f, 0.f};

    STAGE(0, 0);
    __syncthreads();                     // drains vmcnt(0) + barrier

    int buf = 0;
    for (int it = 0; it < KITERS; ++it) {
        if (it + 1 < KITERS) STAGE(buf ^ 1, it + 1);   // async, overlaps MFMAs

        const ushort* as = As[buf];
        const ushort* bs = Bs[buf];
#pragma unroll
        for (int inner = 0; inner < 2; ++inner) {
            const int sw = (((inner * 4 + fq) ^ (fr & 7)) << 3);  // swizzled k-off
            bf16x8 a0 = *(const bf16x8*)(as + (wr + fr) * BK + sw);
            bf16x8 a1 = *(const bf16x8*)(as + (wr + 16 + fr) * BK + sw);
#pragma unroll
            for (int j = 0; j < 4; ++j) {
                bf16x8 bv = *(const bf16x8*)(bs + (wc + j * 16 + fr) * BK + sw);
                acc[0][j] = MFMA(a0, bv, acc[0][j]);
                acc[1][j] = MFMA(a1, bv, acc[1][j]);
            }
        }
        __syncthreads();                 // next-tile DMA drained; reads done
        buf ^= 1;
    }

    // epilogue: Y = bf16( relu(acc + bself + (deg>0)*bneigh) )
#pragma unroll
    for (int i = 0; i < 2; ++i) {
#pragma unroll
        for (int r = 0; r < 4; ++r) {
            int gr = row0 + wr + i * 16 + fq * 4 + r;
            float hb = (gr < N_NODES && deg[gr] > 0.0f) ? 1.0f : 0.0f;
            ushort* yrow = Y + (size_t)gr * DIM;
#pragma unroll
            for (int j = 0; j < 4; ++j) {
                int gc = col0 + wc + j * 16 + fr;
                float v = fmaxf(acc[i][j][r] + bself[gc] + hb * bneigh[gc], 0.f);
                yrow[gc] = f2bf(v);
            }
        }
    }
}

// ---------------------------------------------------------------------------
// LayerNorm: out = LN(h + Y), one 256-thread block per node row.
// ---------------------------------------------------------------------------
__global__ __launch_bounds__(256) void ln_kernel(
    const ushort* __restrict__ Y, const float* __restrict__ h,
    const float* __restrict__ g, const float* __restrict__ b,
    float* __restrict__ out)
{
    __shared__ float red[8];
    int n = blockIdx.x;
    int t = threadIdx.x;
    float2 hv = *(const float2*)(h + (size_t)n * DIM + t * 2);
    ushort2 yv = *(const ushort2*)(Y + (size_t)n * DIM + t * 2);
    float v0 = hv.x + b2f(yv.x);
    float v1 = hv.y + b2f(yv.y);
    float s  = v0 + v1;
    float sq = v0 * v0 + v1 * v1;
#pragma unroll
    for (int off = 32; off >= 1; off >>= 1) {
        s  += __shfl_xor(s, off);
        sq += __shfl_xor(sq, off);
    }
    int wave = t >> 6;
    if ((t & 63) == 0) { red[wave] = s; red[4 + wave] = sq; }
    __syncthreads();
    s  = red[0] + red[1] + red[2] + red[3];
    sq = red[4] + red[5] + red[6] + red[7];
    float mean = s * (1.0f / DIM);
    float var  = sq * (1.0f / DIM) - mean * mean;
    float rstd = rsqrtf(var + 1e-5f);
    float2 gv = *(const float2*)(g + t * 2);
    float2 bv = *(const float2*)(b + t * 2);
    float2 o;
    o.x = (v0 - mean) * rstd * gv.x + bv.x;
    o.y = (v1 - mean) * rstd * gv.y + bv.y;
    *(float2*)(out + (size_t)n * DIM + t * 2) = o;
}

// ---------------------------------------------------------------------------
extern "C" void kernel_launch(void* const* d_in, const int* in_sizes, int n_in,
                              void* d_out, int out_size, void* d_ws, size_t ws_size,
                              hipStream_t stream)
{
    const float* h      = (const float*)d_in[0];
    const int*   eidx   = (const int*)d_in[1];
    const float* Wself  = (const float*)d_in[2];
    const float* bself  = (const float*)d_in[3];
    const float* Wneigh = (const float*)d_in[4];
    const float* bneigh = (const float*)d_in[5];
    const float* gamma  = (const float*)d_in[6];
    const float* beta   = (const float*)d_in[7];
    float* out = (float*)d_out;

    // ws layout: X (20.6MB) | Wc (1MB) | Y (10.3MB) | deg | cnt | col | H8 (5.1MB)
    ushort* X   = (ushort*)d_ws;                          // N_PAD*KDIM bf16
    ushort* Wc  = X + (size_t)N_PAD * KDIM;               // 512*KDIM bf16
    ushort* Y   = Wc + (size_t)DIM * KDIM;                // N_PAD*DIM bf16
    float* deg  = (float*)(Y + (size_t)N_PAD * DIM);      // N f32
    int* cnt    = (int*)(deg + N_NODES);                  // N int
    int* col    = cnt + N_NODES;                          // N*CAP int (2.56MB)
    unsigned char* H8 = (unsigned char*)(col + (size_t)N_NODES * CAP);  // N*DIM fp8

    conv_w<<<(DIM * 128) / 256, 256, 0, stream>>>(Wself, Wneigh, Wc, cnt);
    conv_x<<<(N_PAD * 128) / 256, 256, 0, stream>>>(h, X, H8, eidx, cnt, col);
    gather_agg<<<(N_NODES * 64) / 256, 256, 0, stream>>>(cnt, col, H8, X, deg);

    dim3 gg(DIM / BN, N_PAD / BM);    // (4, 157): col-blocks adjacent
    mfma_gemm<<<gg, 256, 0, stream>>>(X, Wc, deg, bself, bneigh, Y);

    ln_kernel<<<N_NODES, 256, 0, stream>>>(Y, h, gamma, beta, out);
}